// Round 1
// baseline (2302.095 us; speedup 1.0000x reference)
//
#include <hip/hip_runtime.h>
#include <math.h>

#define NB 8192     // batch rows
#define DD 512      // hidden dim
#define KC 4096     // codebook size
#define NL 4        // layers

#define BM 128
#define BN 128
#define BK 32
#define PADL 4
#define NTB (KC / BN)   // 32 column tiles per row

struct Top2 { float v1; int i1; float v2; int i2; };

__device__ __forceinline__ void top2_insert(float v, int idx, float& v1, int& i1, float& v2, int& i2) {
    if (v > v1 || (v == v1 && idx < i1)) { v2 = v1; i2 = i1; v1 = v; i1 = idx; }
    else if (v > v2 || (v == v2 && idx < i2)) { v2 = v; i2 = idx; }
}

__device__ __forceinline__ void pick_better(float av, int ai, float bv, int bi, float& ov, int& oi) {
    if (av > bv || (av == bv && ai < bi)) { ov = av; oi = ai; } else { ov = bv; oi = bi; }
}

// Fused fp32 GEMM (sim = R @ CB^T) with per-(128row x 128code)-tile top-2 epilogue.
__global__ __launch_bounds__(256)
void k_simargmax(const float* __restrict__ R, const float* __restrict__ CB,
                 Top2* __restrict__ part /* [NB][NTB] */)
{
    __shared__ float As[BK][BM + PADL];
    __shared__ float Bs[BK][BN + PADL];
    const int tid = threadIdx.x;
    const int cb0 = blockIdx.x * BN;   // code tile base
    const int rb0 = blockIdx.y * BM;   // row tile base
    const int tm = tid >> 4;           // 0..15 -> 8 rows each
    const int tn = tid & 15;           // 0..15 -> 8 codes each

    float acc[8][8];
#pragma unroll
    for (int i = 0; i < 8; ++i)
#pragma unroll
        for (int j = 0; j < 8; ++j) acc[i][j] = 0.f;

    for (int k0 = 0; k0 < DD; k0 += BK) {
        // stage A (rows) and B (codes) tiles, transposed into [k][m]
#pragma unroll
        for (int it = 0; it < 4; ++it) {
            const int flat = it * 256 + tid;       // 0..1023 float4 slots
            const int r  = flat >> 3;              // 0..127
            const int c4 = (flat & 7) * 4;         // 0,4,..,28
            const float4 a = *reinterpret_cast<const float4*>(R + (size_t)(rb0 + r) * DD + k0 + c4);
            As[c4 + 0][r] = a.x; As[c4 + 1][r] = a.y; As[c4 + 2][r] = a.z; As[c4 + 3][r] = a.w;
            const float4 b = *reinterpret_cast<const float4*>(CB + (size_t)(cb0 + r) * DD + k0 + c4);
            Bs[c4 + 0][r] = b.x; Bs[c4 + 1][r] = b.y; Bs[c4 + 2][r] = b.z; Bs[c4 + 3][r] = b.w;
        }
        __syncthreads();
#pragma unroll
        for (int k = 0; k < BK; ++k) {
            float a[8], b[8];
            *(float4*)&a[0] = *(const float4*)&As[k][tm * 8];
            *(float4*)&a[4] = *(const float4*)&As[k][tm * 8 + 4];
            *(float4*)&b[0] = *(const float4*)&Bs[k][tn * 8];
            *(float4*)&b[4] = *(const float4*)&Bs[k][tn * 8 + 4];
#pragma unroll
            for (int i = 0; i < 8; ++i)
#pragma unroll
                for (int j = 0; j < 8; ++j)
                    acc[i][j] = fmaf(a[i], b[j], acc[i][j]);
        }
        __syncthreads();
    }

    // epilogue: per row, top-2 over this 128-code tile
#pragma unroll
    for (int i = 0; i < 8; ++i) {
        float v1 = -INFINITY, v2 = -INFINITY;
        int   i1 = 0x7fffffff, i2 = 0x7fffffff;
#pragma unroll
        for (int j = 0; j < 8; ++j)
            top2_insert(acc[i][j], tn * 8 + j, v1, i1, v2, i2);
        // reduce across the 16 lanes (same tm) that share this row group
        for (int off = 1; off < 16; off <<= 1) {
            float ov1 = __shfl_xor(v1, off); int oi1 = __shfl_xor(i1, off);
            float ov2 = __shfl_xor(v2, off); int oi2 = __shfl_xor(i2, off);
            if (ov1 > v1 || (ov1 == v1 && oi1 < i1)) {
                float nv2; int ni2; pick_better(v1, i1, ov2, oi2, nv2, ni2);
                v1 = ov1; i1 = oi1; v2 = nv2; i2 = ni2;
            } else {
                float nv2; int ni2; pick_better(v2, i2, ov1, oi1, nv2, ni2);
                v2 = nv2; i2 = ni2;
            }
        }
        if (tn == 0) {
            Top2 p; p.v1 = v1; p.i1 = cb0 + i1; p.v2 = v2; p.i2 = cb0 + i2;
            part[(size_t)(rb0 + tm * 8 + i) * NTB + blockIdx.x] = p;
        }
    }
}

// Per row: exact fp32 re-dot of the 64 candidates, argmax, then residual update,
// residuals_stack write, loss partial, usage scatter; layer NL-1 also writes quantized.
__global__ __launch_bounds__(256)
void k_refine_update(const Top2* __restrict__ part, const float* __restrict__ CB,
                     float* __restrict__ resid, const float* __restrict__ X,
                     float* __restrict__ out_q, float* __restrict__ out_stack,
                     float* __restrict__ out_usage, double* __restrict__ acc_loss,
                     int layer)
{
    __shared__ float row[DD];
    __shared__ int   cand[64];
    __shared__ float wbv[4];
    __shared__ int   wbi[4];
    __shared__ int   s_best;
    __shared__ float red[256];

    const int b = blockIdx.x;
    const int tid = threadIdx.x;

    ((float2*)row)[tid] = ((const float2*)(resid + (size_t)b * DD))[tid];
    if (tid < 64) {
        Top2 p = part[(size_t)b * NTB + (tid >> 1)];
        cand[tid] = (tid & 1) ? p.i2 : p.i1;
    }
    __syncthreads();

    const int wave = tid >> 6;
    const int lane = tid & 63;
    float bestV = -INFINITY;
    int   bestI = 0x7fffffff;
    for (int s = 0; s < 16; ++s) {
        const int ci = cand[wave * 16 + s];
        const float* cr = CB + (size_t)ci * DD;
        float p = 0.f;
#pragma unroll
        for (int q = 0; q < 8; ++q)
            p = fmaf(row[lane * 8 + q], cr[lane * 8 + q], p);
        for (int off = 32; off >= 1; off >>= 1) p += __shfl_xor(p, off);
        if (p > bestV || (p == bestV && ci < bestI)) { bestV = p; bestI = ci; }
    }
    if (lane == 0) { wbv[wave] = bestV; wbi[wave] = bestI; }
    __syncthreads();
    if (tid == 0) {
        float bv = wbv[0]; int bi = wbi[0];
        for (int w = 1; w < 4; ++w)
            if (wbv[w] > bv || (wbv[w] == bv && wbi[w] < bi)) { bv = wbv[w]; bi = wbi[w]; }
        s_best = bi;
        out_usage[layer * KC + bi] = 1.0f;
    }
    __syncthreads();
    const int bi = s_best;

    const float2 c2 = ((const float2*)(CB + (size_t)bi * DD))[tid];
    const float2 r  = ((const float2*)row)[tid];
    float2 rn; rn.x = r.x - c2.x; rn.y = r.y - c2.y;
    ((float2*)(resid + (size_t)b * DD))[tid] = rn;
    // out_stack base is 4-byte aligned only (odd float offset upstream) -> scalar stores
    float* sp = out_stack + ((size_t)b * NL + layer) * DD;
    sp[tid * 2 + 0] = rn.x;
    sp[tid * 2 + 1] = rn.y;
    if (layer == NL - 1) {
        const float2 x2 = ((const float2*)(X + (size_t)b * DD))[tid];
        float2 q; q.x = x2.x - rn.x; q.y = x2.y - rn.y;
        ((float2*)(out_q + (size_t)b * DD))[tid] = q;
    }
    red[tid] = rn.x * rn.x + rn.y * rn.y;
    __syncthreads();
    for (int st = 128; st > 0; st >>= 1) {
        if (tid < st) red[tid] += red[tid + st];
        __syncthreads();
    }
    if (tid == 0) atomicAdd(acc_loss, (double)red[0]);
}

__global__ __launch_bounds__(256)
void k_cbsq(const float* __restrict__ cb, double* __restrict__ acc)
{
    __shared__ double red[256];
    const size_t n = (size_t)NL * KC * DD;
    double s = 0.0;
    for (size_t i = (size_t)blockIdx.x * blockDim.x + threadIdx.x; i < n;
         i += (size_t)gridDim.x * blockDim.x) {
        const float v = cb[i];
        s += (double)v * (double)v;
    }
    red[threadIdx.x] = s;
    __syncthreads();
    for (int st = 128; st > 0; st >>= 1) {
        if (threadIdx.x < st) red[threadIdx.x] += red[threadIdx.x + st];
        __syncthreads();
    }
    if (threadIdx.x == 0) atomicAdd(acc, red[0]);
}

__global__ void k_finalize(const double* __restrict__ accs, float* __restrict__ out_loss)
{
    const double loss = (accs[0] / ((double)NB * DD) + 0.01 * (accs[1] / ((double)NL * KC))) / (double)DD;
    out_loss[0] = (float)loss;
}

extern "C" void kernel_launch(void* const* d_in, const int* in_sizes, int n_in,
                              void* d_out, int out_size, void* d_ws, size_t ws_size,
                              hipStream_t stream)
{
    (void)in_sizes; (void)n_in; (void)out_size; (void)ws_size;
    const float* x  = (const float*)d_in[0];
    // d_in[1] = temperature: positive scale, argmax-invariant, soft path cancels -> unused
    const float* cb = (const float*)d_in[2];

    float* out       = (float*)d_out;
    float* out_q     = out;                                   // [NB, DD]
    float* out_loss  = out + (size_t)NB * DD;                 // [1]
    float* out_stack = out_loss + 1;                          // [NB, NL, DD]
    float* out_usage = out_stack + (size_t)NB * NL * DD;      // [NL, KC]

    char* ws = (char*)d_ws;
    float* resid = (float*)ws;                                // 16 MB
    Top2*  part  = (Top2*)(ws + (size_t)16 * 1024 * 1024);    // 4 MB
    double* accs = (double*)(ws + (size_t)20 * 1024 * 1024);  // [0]=sum r^2, [1]=sum cb^2

    hipMemsetAsync(accs, 0, 2 * sizeof(double), stream);
    hipMemsetAsync(out_usage, 0, (size_t)NL * KC * sizeof(float), stream);
    hipMemcpyAsync(resid, x, (size_t)NB * DD * sizeof(float), hipMemcpyDeviceToDevice, stream);

    k_cbsq<<<1024, 256, 0, stream>>>(cb, accs + 1);

    for (int l = 0; l < NL; ++l) {
        const float* cbl = cb + (size_t)l * KC * DD;
        k_simargmax<<<dim3(KC / BN, NB / BM), 256, 0, stream>>>(resid, cbl, part);
        k_refine_update<<<NB, 256, 0, stream>>>(part, cbl, resid, x, out_q, out_stack,
                                                out_usage, accs, l);
    }
    k_finalize<<<1, 1, 0, stream>>>(accs, out_loss);
}

// Round 2
// 1083.549 us; speedup vs baseline: 2.1246x; 2.1246x over previous
//
#include <hip/hip_runtime.h>
#include <math.h>

#define NB 8192     // batch rows
#define DD 512      // hidden dim
#define KC 4096     // codebook size
#define NL 4        // layers

#define BM 128
#define BN 128
#define NTB (KC / BN)   // 32 column tiles
#define MARGIN 4.0f     // bf16-dot candidate margin (>> 2*max bf16 dot error ~0.5)

typedef __bf16 bf16x8 __attribute__((ext_vector_type(8)));
typedef float  f32x4  __attribute__((ext_vector_type(4)));
typedef unsigned short u16;

struct Top2 { float v1; int i1; float v2; int i2; };

#define GLOAD16(gp, lp) __builtin_amdgcn_global_load_lds( \
    (const __attribute__((address_space(1))) void*)(gp),  \
    (__attribute__((address_space(3))) void*)(lp), 16, 0, 0)

__device__ __forceinline__ u16 f2bf(float f) {   // RNE fp32 -> bf16
    unsigned u = __float_as_uint(f);
    return (u16)((u + 0x7fffu + ((u >> 16) & 1u)) >> 16);
}

__device__ __forceinline__ void top2_insert(float v, int idx, float& v1, int& i1, float& v2, int& i2) {
    if (v > v1 || (v == v1 && idx < i1)) { v2 = v1; i2 = i1; v1 = v; i1 = idx; }
    else if (v > v2 || (v == v2 && idx < i2)) { v2 = v; i2 = idx; }
}

__device__ __forceinline__ void pick_better(float av, int ai, float bv, int bi, float& ov, int& oi) {
    if (av > bv || (av == bv && ai < bi)) { ov = av; oi = ai; } else { ov = bv; oi = bi; }
}

// fp32 -> bf16 bulk convert (n4 = count/4)
__global__ __launch_bounds__(256)
void k_cvt_bf16(const float* __restrict__ src, u16* __restrict__ dst, int n4)
{
    const int i = blockIdx.x * 256 + threadIdx.x;
    if (i < n4) {
        const float4 f = ((const float4*)src)[i];
        uint2 p;
        p.x = (unsigned)f2bf(f.x) | ((unsigned)f2bf(f.y) << 16);
        p.y = (unsigned)f2bf(f.z) | ((unsigned)f2bf(f.w) << 16);
        ((uint2*)dst)[i] = p;
    }
}

// bf16 MFMA GEMM: sim = Rb [NB x DD] @ Cb^T [KC x DD], fused per-row top-2 over each
// 128-code tile. 128x128 tile, 4 waves (2x2), 4x4 16x16x32 fragments, BK=32,
// double-buffered LDS via global_load_lds(16B) with source-side XOR swizzle.
__global__ __launch_bounds__(256)
void k_simtop2(const u16* __restrict__ Rb, const u16* __restrict__ Cb,
               Top2* __restrict__ part /* [NB][NTB] */)
{
    __shared__ __align__(16) u16 As[2][4096];   // [buf][128 rows x 32 k]
    __shared__ __align__(16) u16 Bs[2][4096];
    __shared__ Top2 mrg[BM][2];

    const int tid  = threadIdx.x;
    const int lane = tid & 63;
    const int w    = tid >> 6;
    const int wr   = w >> 1, wc = w & 1;
    const int cb0  = blockIdx.x * BN;
    const int rb0  = blockIdx.y * BM;

    // staging: linear LDS byte o = tid*16 (+4096 for second load); row r=o>>6,
    // 16B slot s=(o>>4)&3; fetch global k-slot s^(r&3) (both-sides swizzle).
    const int o  = tid << 4;
    const int rr = o >> 6;                       // 0..63
    const int ss = ((o >> 4) & 3) ^ (rr & 3);
    const char* gA = (const char*)Rb + (((size_t)(rb0 + rr)) << 10) + (ss << 4);
    const char* gB = (const char*)Cb + (((size_t)(cb0 + rr)) << 10) + (ss << 4);
    char* ldsA = (char*)&As[0][0];
    char* ldsB = (char*)&Bs[0][0];
    char* dA = ldsA + o;
    char* dB = ldsB + o;

    // fragment reads: row = wsub*64 + m*16 + (lane&15), k-slot lane>>4, swizzled
    const int slotR = (((lane >> 4) ^ (lane & 3)) << 4);
    const int aoff = (wr * 64 + (lane & 15)) * 64 + slotR;
    const int boff = (wc * 64 + (lane & 15)) * 64 + slotR;

    f32x4 acc[4][4];
    const f32x4 zero = {0.f, 0.f, 0.f, 0.f};
#pragma unroll
    for (int m = 0; m < 4; ++m)
#pragma unroll
        for (int n = 0; n < 4; ++n) acc[m][n] = zero;

    // prologue: stage K-tile 0 into buffer 0
    GLOAD16(gA, dA);
    GLOAD16(gA + 65536, dA + 4096);
    GLOAD16(gB, dB);
    GLOAD16(gB + 65536, dB + 4096);
    __syncthreads();   // drains vmcnt

    int cur = 0;
#pragma unroll 1
    for (int t = 1; t <= 16; ++t) {
        if (t < 16) {           // stage next K-tile into other buffer
            const int nb = (cur ^ 1) * 8192;
            GLOAD16(gA + t * 64,         dA + nb);
            GLOAD16(gA + 65536 + t * 64, dA + nb + 4096);
            GLOAD16(gB + t * 64,         dB + nb);
            GLOAD16(gB + 65536 + t * 64, dB + nb + 4096);
        }
        const char* bA = ldsA + cur * 8192;
        const char* bB = ldsB + cur * 8192;
        bf16x8 a[4], b[4];
#pragma unroll
        for (int m = 0; m < 4; ++m) a[m] = *(const bf16x8*)(bA + aoff + m * 1024);
#pragma unroll
        for (int n = 0; n < 4; ++n) b[n] = *(const bf16x8*)(bB + boff + n * 1024);
#pragma unroll
        for (int m = 0; m < 4; ++m)
#pragma unroll
            for (int n = 0; n < 4; ++n)
                acc[m][n] = __builtin_amdgcn_mfma_f32_16x16x32_bf16(a[m], b[n], acc[m][n], 0, 0, 0);
        __syncthreads();        // drain next-tile loads + protect buffer swap
        cur ^= 1;
    }

    // epilogue: C[row][col]: col = lane&15 (code), row = (lane>>4)*4 + j (batch)
    const int rgrp = lane >> 4;
    const int cidx = lane & 15;
#pragma unroll
    for (int m = 0; m < 4; ++m) {
#pragma unroll
        for (int j = 0; j < 4; ++j) {
            float v1 = -INFINITY, v2 = -INFINITY;
            int   i1 = 0x7fffffff, i2 = 0x7fffffff;
#pragma unroll
            for (int n = 0; n < 4; ++n)
                top2_insert(acc[m][n][j], cb0 + wc * 64 + n * 16 + cidx, v1, i1, v2, i2);
            for (int off = 1; off < 16; off <<= 1) {
                float ov1 = __shfl_xor(v1, off); int oi1 = __shfl_xor(i1, off);
                float ov2 = __shfl_xor(v2, off); int oi2 = __shfl_xor(i2, off);
                if (ov1 > v1 || (ov1 == v1 && oi1 < i1)) {
                    float nv2; int ni2; pick_better(v1, i1, ov2, oi2, nv2, ni2);
                    v1 = ov1; i1 = oi1; v2 = nv2; i2 = ni2;
                } else {
                    float nv2; int ni2; pick_better(v2, i2, ov1, oi1, nv2, ni2);
                    v2 = nv2; i2 = ni2;
                }
            }
            if (cidx == 0) {
                Top2 p; p.v1 = v1; p.i1 = i1; p.v2 = v2; p.i2 = i2;
                mrg[wr * 64 + m * 16 + rgrp * 4 + j][wc] = p;
            }
        }
    }
    __syncthreads();
    if (tid < BM) {
        Top2 a = mrg[tid][0], c = mrg[tid][1];
        float v1 = a.v1, v2 = a.v2; int i1 = a.i1, i2 = a.i2;
        top2_insert(c.v1, c.i1, v1, i1, v2, i2);
        top2_insert(c.v2, c.i2, v1, i1, v2, i2);
        Top2 p; p.v1 = v1; p.i1 = i1; p.v2 = v2; p.i2 = i2;
        part[(size_t)(rb0 + tid) * NTB + blockIdx.x] = p;
    }
}

// Per row: exact fp32 re-dot of candidates within MARGIN of the bf16 max, argmax,
// residual update (fp32 chain via out_stack + bf16 mirror for next GEMM), loss,
// usage; layer NL-1 also writes quantized = x - r.
__global__ __launch_bounds__(256)
void k_refine(const Top2* __restrict__ part, const float* __restrict__ CB,
              const float* __restrict__ prevBase, size_t prevStride,
              const float* __restrict__ X, float* __restrict__ out_q,
              float* __restrict__ stack, u16* __restrict__ residb,
              float* __restrict__ out_usage, double* __restrict__ acc_loss,
              int layer)
{
    __shared__ float row[DD];
    __shared__ float candV[64];
    __shared__ int   candI[64];
    __shared__ float s_thr;
    __shared__ float wbv[4];
    __shared__ int   wbi[4];
    __shared__ int   s_best;
    __shared__ float red[256];

    const int b = blockIdx.x;
    const int tid = threadIdx.x;
    const float* pr = prevBase + (size_t)b * prevStride;
    row[tid]       = pr[tid];
    row[tid + 256] = pr[tid + 256];
    if (tid < 64) {
        Top2 p = part[(size_t)b * NTB + (tid >> 1)];
        candV[tid] = (tid & 1) ? p.v2 : p.v1;
        candI[tid] = (tid & 1) ? p.i2 : p.i1;
    }
    __syncthreads();
    if (tid < 64) {
        float v = candV[tid];
        for (int off = 1; off < 64; off <<= 1) v = fmaxf(v, __shfl_xor(v, off));
        if (tid == 0) s_thr = v - MARGIN;
    }
    __syncthreads();
    const float thr = s_thr;

    const int wave = tid >> 6;
    const int lane = tid & 63;
    float bestV = -INFINITY;
    int   bestI = 0x7fffffff;
    for (int s = 0; s < 16; ++s) {
        const int c = wave * 16 + s;
        if (candV[c] < thr) continue;          // wave-uniform skip
        const int ci = candI[c];
        const float* cr = CB + (size_t)ci * DD;
        float p = 0.f;
#pragma unroll
        for (int q = 0; q < 8; ++q)
            p = fmaf(row[lane * 8 + q], cr[lane * 8 + q], p);
        for (int off = 32; off >= 1; off >>= 1) p += __shfl_xor(p, off);
        if (p > bestV || (p == bestV && ci < bestI)) { bestV = p; bestI = ci; }
    }
    if (lane == 0) { wbv[wave] = bestV; wbi[wave] = bestI; }
    __syncthreads();
    if (tid == 0) {
        float bv = wbv[0]; int bi = wbi[0];
        for (int k = 1; k < 4; ++k)
            if (wbv[k] > bv || (wbv[k] == bv && wbi[k] < bi)) { bv = wbv[k]; bi = wbi[k]; }
        s_best = bi;
        out_usage[layer * KC + bi] = 1.0f;
    }
    __syncthreads();
    const int bi = s_best;

    const float* cr = CB + (size_t)bi * DD;
    const float rn0 = row[tid]       - cr[tid];
    const float rn1 = row[tid + 256] - cr[tid + 256];
    float* sp = stack + ((size_t)b * NL + layer) * DD;   // base is odd-aligned -> scalar
    sp[tid]       = rn0;
    sp[tid + 256] = rn1;
    residb[(size_t)b * DD + tid]       = f2bf(rn0);
    residb[(size_t)b * DD + tid + 256] = f2bf(rn1);
    if (layer == NL - 1) {
        out_q[(size_t)b * DD + tid]       = X[(size_t)b * DD + tid]       - rn0;
        out_q[(size_t)b * DD + tid + 256] = X[(size_t)b * DD + tid + 256] - rn1;
    }
    red[tid] = rn0 * rn0 + rn1 * rn1;
    __syncthreads();
    for (int st = 128; st > 0; st >>= 1) {
        if (tid < st) red[tid] += red[tid + st];
        __syncthreads();
    }
    if (tid == 0) atomicAdd(acc_loss, (double)red[0]);
}

__global__ __launch_bounds__(256)
void k_cbsq(const float* __restrict__ cb, double* __restrict__ acc)
{
    __shared__ double red[256];
    const size_t n = (size_t)NL * KC * DD;
    double s = 0.0;
    for (size_t i = (size_t)blockIdx.x * blockDim.x + threadIdx.x; i < n;
         i += (size_t)gridDim.x * blockDim.x) {
        const float v = cb[i];
        s += (double)v * (double)v;
    }
    red[threadIdx.x] = s;
    __syncthreads();
    for (int st = 128; st > 0; st >>= 1) {
        if (threadIdx.x < st) red[threadIdx.x] += red[threadIdx.x + st];
        __syncthreads();
    }
    if (threadIdx.x == 0) atomicAdd(acc, red[0]);
}

__global__ void k_finalize(const double* __restrict__ accs, float* __restrict__ out_loss)
{
    const double loss = (accs[0] / ((double)NB * DD) + 0.01 * (accs[1] / ((double)NL * KC))) / (double)DD;
    out_loss[0] = (float)loss;
}

extern "C" void kernel_launch(void* const* d_in, const int* in_sizes, int n_in,
                              void* d_out, int out_size, void* d_ws, size_t ws_size,
                              hipStream_t stream)
{
    (void)in_sizes; (void)n_in; (void)out_size; (void)ws_size;
    const float* x  = (const float*)d_in[0];
    // d_in[1] = temperature: positive scale, argmax-invariant, soft path cancels -> unused
    const float* cb = (const float*)d_in[2];

    float* out       = (float*)d_out;
    float* out_q     = out;                                   // [NB, DD]
    float* out_loss  = out + (size_t)NB * DD;                 // [1]
    float* out_stack = out_loss + 1;                          // [NB, NL, DD] (fp32 residual chain lives here)
    float* out_usage = out_stack + (size_t)NB * NL * DD;      // [NL, KC]

    char* ws = (char*)d_ws;
    Top2* part    = (Top2*)ws;                                // 4 MB
    u16*  residb  = (u16*)(ws + ((size_t)4 << 20));           // 8 MB bf16 residual mirror
    u16*  cbb     = (u16*)(ws + ((size_t)12 << 20));          // 4 MB bf16 codebook (per layer)
    double* accs  = (double*)(ws + ((size_t)16 << 20));       // [0]=sum r^2, [1]=sum cb^2

    hipMemsetAsync(accs, 0, 2 * sizeof(double), stream);
    hipMemsetAsync(out_usage, 0, (size_t)NL * KC * sizeof(float), stream);

    k_cvt_bf16<<<(NB * DD / 4 + 255) / 256, 256, 0, stream>>>(x, residb, NB * DD / 4);
    k_cbsq<<<1024, 256, 0, stream>>>(cb, accs + 1);

    for (int l = 0; l < NL; ++l) {
        const float* cbl = cb + (size_t)l * KC * DD;
        k_cvt_bf16<<<(KC * DD / 4 + 255) / 256, 256, 0, stream>>>(cbl, cbb, KC * DD / 4);
        k_simtop2<<<dim3(NTB, NB / BM), 256, 0, stream>>>(residb, cbb, part);
        const float* prevBase = (l == 0) ? x : (out_stack + (size_t)(l - 1) * DD);
        const size_t prevStride = (l == 0) ? (size_t)DD : (size_t)NL * DD;
        k_refine<<<NB, 256, 0, stream>>>(part, cbl, prevBase, prevStride, x, out_q,
                                         out_stack, residb, out_usage, accs, l);
    }
    k_finalize<<<1, 1, 0, stream>>>(accs, out_loss);
}

// Round 3
// 1070.867 us; speedup vs baseline: 2.1497x; 1.0118x over previous
//
#include <hip/hip_runtime.h>
#include <math.h>

#define NB 8192     // batch rows
#define DD 512      // hidden dim
#define KC 4096     // codebook size
#define NL 4        // layers

#define BM 128
#define BN 128
#define NTB (KC / BN)   // 32 column tiles
#define MARGIN 4.0f     // bf16-dot candidate margin (>> 2*max bf16 dot error ~0.5)

typedef __bf16 bf16x8 __attribute__((ext_vector_type(8)));
typedef float  f32x4  __attribute__((ext_vector_type(4)));
typedef unsigned short u16;

struct Top2 { float v1; int i1; float v2; int i2; };

#define GLOAD16(gp, lp) __builtin_amdgcn_global_load_lds( \
    (const __attribute__((address_space(1))) void*)(gp),  \
    (__attribute__((address_space(3))) void*)(lp), 16, 0, 0)

__device__ __forceinline__ u16 f2bf(float f) {   // RNE fp32 -> bf16
    unsigned u = __float_as_uint(f);
    return (u16)((u + 0x7fffu + ((u >> 16) & 1u)) >> 16);
}

__device__ __forceinline__ void top2_insert(float v, int idx, float& v1, int& i1, float& v2, int& i2) {
    if (v > v1 || (v == v1 && idx < i1)) { v2 = v1; i2 = i1; v1 = v; i1 = idx; }
    else if (v > v2 || (v == v2 && idx < i2)) { v2 = v; i2 = idx; }
}

__device__ __forceinline__ void pick_better(float av, int ai, float bv, int bi, float& ov, int& oi) {
    if (av > bv || (av == bv && ai < bi)) { ov = av; oi = ai; } else { ov = bv; oi = bi; }
}

// fp32 -> bf16 bulk convert (n4 = count/4)
__global__ __launch_bounds__(256)
void k_cvt_bf16(const float* __restrict__ src, u16* __restrict__ dst, int n4)
{
    const int i = blockIdx.x * 256 + threadIdx.x;
    if (i < n4) {
        const float4 f = ((const float4*)src)[i];
        uint2 p;
        p.x = (unsigned)f2bf(f.x) | ((unsigned)f2bf(f.y) << 16);
        p.y = (unsigned)f2bf(f.z) | ((unsigned)f2bf(f.w) << 16);
        ((uint2*)dst)[i] = p;
    }
}

// bf16 MFMA GEMM: sim = Rb [NB x DD] @ Cb^T [KC x DD], fused per-row top-2 over each
// 128-code tile. 128x128 tile, 4 waves (2x2), 4x4 16x16x32 fragments, BK=32.
// 3-deep LDS ring staged via global_load_lds(16B), counted vmcnt + raw s_barrier
// (never drains prefetch queue), source-side XOR swizzle (2-way banks on ds_read),
// 2D XCD chunking (16x16 blocks/XCD: A 2MB + B 2MB ~= one XCD L2).
__global__ __launch_bounds__(256)
void k_simtop2(const u16* __restrict__ Rb, const u16* __restrict__ Cb,
               Top2* __restrict__ part /* [NB][NTB] */)
{
    // ring[b]: A tile bytes [0,8192) = 128 rows x 64B, B tile bytes [8192,16384)
    __shared__ __align__(16) u16 ring[3][8192];
    __shared__ Top2 mrg[BM][2];

    const int tid  = threadIdx.x;
    const int lane = tid & 63;
    const int w    = tid >> 6;
    const int wr   = w >> 1, wc = w & 1;

    // 2D XCD chunking: linear bid -> xcd (round-robin) -> 16x16 chunk
    const int bid      = blockIdx.y * gridDim.x + blockIdx.x;  // 0..2047
    const int xcd      = bid & 7;
    const int idx      = bid >> 3;                             // 0..255
    const int row_pan  = (xcd >> 1) * 16 + (idx >> 4);         // 0..63
    const int col_tile = (xcd & 1) * 16 + (idx & 15);          // 0..31
    const int rb0 = row_pan * BM;
    const int cb0 = col_tile * BN;

    // staging: LDS dest o = tid*16 (linear, rows r=o>>6 in 0..63; +4096 -> rows 64..127)
    // global 16B k-slot fetched = slot ^ ((row>>1)&3)  (involution; reader applies same)
    const int o  = tid << 4;
    const int rr = o >> 6;
    const int sg = ((o >> 4) & 3) ^ ((rr >> 1) & 3);
    const char* gA = (const char*)Rb + (((size_t)(rb0 + rr)) << 10) + (sg << 4);
    const char* gB = (const char*)Cb + (((size_t)(cb0 + rr)) << 10) + (sg << 4);
    char* ldsbase = (char*)&ring[0][0];

#define STAGE(t, b) do {                                   \
        char* _d = ldsbase + (b) * 16384;                  \
        GLOAD16(gA + (t) * 64,         _d + o);            \
        GLOAD16(gA + 65536 + (t) * 64, _d + o + 4096);     \
        GLOAD16(gB + (t) * 64,         _d + 8192 + o);     \
        GLOAD16(gB + 65536 + (t) * 64, _d + 8192 + o + 4096); \
    } while (0)

    // fragment reads: row = wsub*64 + m*16 + (lane&15), k-slot = lane>>4, swizzled.
    // ((row>>1)&3) is invariant under row += 16/64 -> same xor term for all m.
    const int slotR = (((lane >> 4) ^ (((lane & 15) >> 1) & 3)) << 4);
    const int aoff = (wr * 64 + (lane & 15)) * 64 + slotR;
    const int boff = (wc * 64 + (lane & 15)) * 64 + slotR;

    f32x4 acc[4][4];
    const f32x4 zero = {0.f, 0.f, 0.f, 0.f};
#pragma unroll
    for (int m = 0; m < 4; ++m)
#pragma unroll
        for (int n = 0; n < 4; ++n) acc[m][n] = zero;

    // prologue: tiles 0,1 -> bufs 0,1  (8 outstanding vmem/wave)
    STAGE(0, 0);
    STAGE(1, 1);

    int cur = 0, nxt = 2;
#pragma unroll 1
    for (int t = 0; t < 16; ++t) {
        // tile t complete once own vmcnt <= 4 (only t+1 in flight); barrier makes it
        // block-wide AND guarantees everyone finished reading buf (t-1) == buf (t+2)%3.
        if (t < 15) asm volatile("s_waitcnt vmcnt(4)" ::: "memory");
        else        asm volatile("s_waitcnt vmcnt(0)" ::: "memory");
        __builtin_amdgcn_s_barrier();
        asm volatile("" ::: "memory");
        if (t + 2 < 16) STAGE(t + 2, nxt);

        const char* bA = ldsbase + cur * 16384;
        bf16x8 a[4], b[4];
#pragma unroll
        for (int m = 0; m < 4; ++m) a[m] = *(const bf16x8*)(bA + aoff + m * 1024);
#pragma unroll
        for (int n = 0; n < 4; ++n) b[n] = *(const bf16x8*)(bA + 8192 + boff + n * 1024);
#pragma unroll
        for (int m = 0; m < 4; ++m)
#pragma unroll
            for (int n = 0; n < 4; ++n)
                acc[m][n] = __builtin_amdgcn_mfma_f32_16x16x32_bf16(a[m], b[n], acc[m][n], 0, 0, 0);

        cur = (cur == 2) ? 0 : cur + 1;
        nxt = (nxt == 2) ? 0 : nxt + 1;
    }
#undef STAGE

    // epilogue: C[row][col]: col = lane&15 (code), row = (lane>>4)*4 + j (batch)
    const int rgrp = lane >> 4;
    const int cidx = lane & 15;
#pragma unroll
    for (int m = 0; m < 4; ++m) {
#pragma unroll
        for (int j = 0; j < 4; ++j) {
            float v1 = -INFINITY, v2 = -INFINITY;
            int   i1 = 0x7fffffff, i2 = 0x7fffffff;
#pragma unroll
            for (int n = 0; n < 4; ++n)
                top2_insert(acc[m][n][j], cb0 + wc * 64 + n * 16 + cidx, v1, i1, v2, i2);
            for (int off = 1; off < 16; off <<= 1) {
                float ov1 = __shfl_xor(v1, off); int oi1 = __shfl_xor(i1, off);
                float ov2 = __shfl_xor(v2, off); int oi2 = __shfl_xor(i2, off);
                if (ov1 > v1 || (ov1 == v1 && oi1 < i1)) {
                    float nv2; int ni2; pick_better(v1, i1, ov2, oi2, nv2, ni2);
                    v1 = ov1; i1 = oi1; v2 = nv2; i2 = ni2;
                } else {
                    float nv2; int ni2; pick_better(v2, i2, ov1, oi1, nv2, ni2);
                    v2 = nv2; i2 = ni2;
                }
            }
            if (cidx == 0) {
                Top2 p; p.v1 = v1; p.i1 = i1; p.v2 = v2; p.i2 = i2;
                mrg[wr * 64 + m * 16 + rgrp * 4 + j][wc] = p;
            }
        }
    }
    __syncthreads();
    if (tid < BM) {
        Top2 a = mrg[tid][0], c = mrg[tid][1];
        float v1 = a.v1, v2 = a.v2; int i1 = a.i1, i2 = a.i2;
        top2_insert(c.v1, c.i1, v1, i1, v2, i2);
        top2_insert(c.v2, c.i2, v1, i1, v2, i2);
        Top2 p; p.v1 = v1; p.i1 = i1; p.v2 = v2; p.i2 = i2;
        part[(size_t)(rb0 + tid) * NTB + col_tile] = p;
    }
}

// Per row: exact fp32 re-dot of candidates within MARGIN of the bf16 max, argmax,
// residual update (fp32 chain via out_stack + bf16 mirror for next GEMM), loss,
// usage; layer NL-1 also writes quantized = x - r.
__global__ __launch_bounds__(256)
void k_refine(const Top2* __restrict__ part, const float* __restrict__ CB,
              const float* __restrict__ prevBase, size_t prevStride,
              const float* __restrict__ X, float* __restrict__ out_q,
              float* __restrict__ stack, u16* __restrict__ residb,
              float* __restrict__ out_usage, double* __restrict__ acc_loss,
              int layer)
{
    __shared__ float row[DD];
    __shared__ float candV[64];
    __shared__ int   candI[64];
    __shared__ float s_thr;
    __shared__ float wbv[4];
    __shared__ int   wbi[4];
    __shared__ int   s_best;
    __shared__ float red[256];

    const int b = blockIdx.x;
    const int tid = threadIdx.x;
    const float* pr = prevBase + (size_t)b * prevStride;
    row[tid]       = pr[tid];
    row[tid + 256] = pr[tid + 256];
    if (tid < 64) {
        Top2 p = part[(size_t)b * NTB + (tid >> 1)];
        candV[tid] = (tid & 1) ? p.v2 : p.v1;
        candI[tid] = (tid & 1) ? p.i2 : p.i1;
    }
    __syncthreads();
    if (tid < 64) {
        float v = candV[tid];
        for (int off = 1; off < 64; off <<= 1) v = fmaxf(v, __shfl_xor(v, off));
        if (tid == 0) s_thr = v - MARGIN;
    }
    __syncthreads();
    const float thr = s_thr;

    const int wave = tid >> 6;
    const int lane = tid & 63;
    float bestV = -INFINITY;
    int   bestI = 0x7fffffff;
    for (int s = 0; s < 16; ++s) {
        const int c = wave * 16 + s;
        if (candV[c] < thr) continue;          // wave-uniform skip
        const int ci = candI[c];
        const float* cr = CB + (size_t)ci * DD;
        float p = 0.f;
#pragma unroll
        for (int q = 0; q < 8; ++q)
            p = fmaf(row[lane * 8 + q], cr[lane * 8 + q], p);
        for (int off = 32; off >= 1; off >>= 1) p += __shfl_xor(p, off);
        if (p > bestV || (p == bestV && ci < bestI)) { bestV = p; bestI = ci; }
    }
    if (lane == 0) { wbv[wave] = bestV; wbi[wave] = bestI; }
    __syncthreads();
    if (tid == 0) {
        float bv = wbv[0]; int bi = wbi[0];
        for (int k = 1; k < 4; ++k)
            if (wbv[k] > bv || (wbv[k] == bv && wbi[k] < bi)) { bv = wbv[k]; bi = wbi[k]; }
        s_best = bi;
        out_usage[layer * KC + bi] = 1.0f;
    }
    __syncthreads();
    const int bi = s_best;

    const float* cr = CB + (size_t)bi * DD;
    const float rn0 = row[tid]       - cr[tid];
    const float rn1 = row[tid + 256] - cr[tid + 256];
    float* sp = stack + ((size_t)b * NL + layer) * DD;   // base is odd-aligned -> scalar
    sp[tid]       = rn0;
    sp[tid + 256] = rn1;
    residb[(size_t)b * DD + tid]       = f2bf(rn0);
    residb[(size_t)b * DD + tid + 256] = f2bf(rn1);
    if (layer == NL - 1) {
        out_q[(size_t)b * DD + tid]       = X[(size_t)b * DD + tid]       - rn0;
        out_q[(size_t)b * DD + tid + 256] = X[(size_t)b * DD + tid + 256] - rn1;
    }
    red[tid] = rn0 * rn0 + rn1 * rn1;
    __syncthreads();
    for (int st = 128; st > 0; st >>= 1) {
        if (tid < st) red[tid] += red[tid + st];
        __syncthreads();
    }
    if (tid == 0) atomicAdd(acc_loss, (double)red[0]);
}

__global__ __launch_bounds__(256)
void k_cbsq(const float* __restrict__ cb, double* __restrict__ acc)
{
    __shared__ double red[256];
    const size_t n = (size_t)NL * KC * DD;
    double s = 0.0;
    for (size_t i = (size_t)blockIdx.x * blockDim.x + threadIdx.x; i < n;
         i += (size_t)gridDim.x * blockDim.x) {
        const float v = cb[i];
        s += (double)v * (double)v;
    }
    red[threadIdx.x] = s;
    __syncthreads();
    for (int st = 128; st > 0; st >>= 1) {
        if (threadIdx.x < st) red[threadIdx.x] += red[threadIdx.x + st];
        __syncthreads();
    }
    if (threadIdx.x == 0) atomicAdd(acc, red[0]);
}

__global__ void k_finalize(const double* __restrict__ accs, float* __restrict__ out_loss)
{
    const double loss = (accs[0] / ((double)NB * DD) + 0.01 * (accs[1] / ((double)NL * KC))) / (double)DD;
    out_loss[0] = (float)loss;
}

extern "C" void kernel_launch(void* const* d_in, const int* in_sizes, int n_in,
                              void* d_out, int out_size, void* d_ws, size_t ws_size,
                              hipStream_t stream)
{
    (void)in_sizes; (void)n_in; (void)out_size; (void)ws_size;
    const float* x  = (const float*)d_in[0];
    // d_in[1] = temperature: positive scale, argmax-invariant, soft path cancels -> unused
    const float* cb = (const float*)d_in[2];

    float* out       = (float*)d_out;
    float* out_q     = out;                                   // [NB, DD]
    float* out_loss  = out + (size_t)NB * DD;                 // [1]
    float* out_stack = out_loss + 1;                          // [NB, NL, DD] (fp32 residual chain lives here)
    float* out_usage = out_stack + (size_t)NB * NL * DD;      // [NL, KC]

    char* ws = (char*)d_ws;
    Top2* part    = (Top2*)ws;                                // 4 MB
    u16*  residb  = (u16*)(ws + ((size_t)4 << 20));           // 8 MB bf16 residual mirror
    u16*  cbb     = (u16*)(ws + ((size_t)12 << 20));          // 4 MB bf16 codebook (per layer)
    double* accs  = (double*)(ws + ((size_t)16 << 20));       // [0]=sum r^2, [1]=sum cb^2

    hipMemsetAsync(accs, 0, 2 * sizeof(double), stream);
    hipMemsetAsync(out_usage, 0, (size_t)NL * KC * sizeof(float), stream);

    k_cvt_bf16<<<(NB * DD / 4 + 255) / 256, 256, 0, stream>>>(x, residb, NB * DD / 4);
    k_cbsq<<<1024, 256, 0, stream>>>(cb, accs + 1);

    for (int l = 0; l < NL; ++l) {
        const float* cbl = cb + (size_t)l * KC * DD;
        k_cvt_bf16<<<(KC * DD / 4 + 255) / 256, 256, 0, stream>>>(cbl, cbb, KC * DD / 4);
        k_simtop2<<<dim3(NTB, NB / BM), 256, 0, stream>>>(residb, cbb, part);
        const float* prevBase = (l == 0) ? x : (out_stack + (size_t)(l - 1) * DD);
        const size_t prevStride = (l == 0) ? (size_t)DD : (size_t)NL * DD;
        k_refine<<<NB, 256, 0, stream>>>(part, cbl, prevBase, prevStride, x, out_q,
                                         out_stack, residb, out_usage, accs, l);
    }
    k_finalize<<<1, 1, 0, stream>>>(accs, out_loss);
}

// Round 4
// 814.856 us; speedup vs baseline: 2.8252x; 1.3142x over previous
//
#include <hip/hip_runtime.h>
#include <math.h>

#define NB 8192     // batch rows
#define DD 512      // hidden dim
#define KC 4096     // codebook size
#define NL 4        // layers

#define NTB 32      // part[] column tiles (128 codes each) -- same as R2/R3
#define MARGIN 4.0f // bf16-dot candidate margin (>> 2*max bf16 dot error ~0.3)

// GEMM geometry: 256x256 tile, BK=64, 8 waves (2M x 4N), 8-phase schedule
#define GBM 256
#define GBN 256

typedef __bf16 bf16x8 __attribute__((ext_vector_type(8)));
typedef float  f32x4  __attribute__((ext_vector_type(4)));
typedef unsigned short u16;

struct Top2 { float v1; int i1; float v2; int i2; };

#define GLOAD16(gp, lp) __builtin_amdgcn_global_load_lds( \
    (const __attribute__((address_space(1))) void*)(gp),  \
    (__attribute__((address_space(3))) void*)(lp), 16, 0, 0)

__device__ __forceinline__ u16 f2bf(float f) {   // RNE fp32 -> bf16
    unsigned u = __float_as_uint(f);
    return (u16)((u + 0x7fffu + ((u >> 16) & 1u)) >> 16);
}

__device__ __forceinline__ void top2_insert(float v, int idx, float& v1, int& i1, float& v2, int& i2) {
    if (v > v1 || (v == v1 && idx < i1)) { v2 = v1; i2 = i1; v1 = v; i1 = idx; }
    else if (v > v2 || (v == v2 && idx < i2)) { v2 = v; i2 = idx; }
}

__device__ __forceinline__ void pick_better(float av, int ai, float bv, int bi, float& ov, int& oi) {
    if (av > bv || (av == bv && ai < bi)) { ov = av; oi = ai; } else { ov = bv; oi = bi; }
}

// fp32 -> bf16 bulk convert (n4 = count/4)
__global__ __launch_bounds__(256)
void k_cvt_bf16(const float* __restrict__ src, u16* __restrict__ dst, int n4)
{
    const int i = blockIdx.x * 256 + threadIdx.x;
    if (i < n4) {
        const float4 f = ((const float4*)src)[i];
        uint2 p;
        p.x = (unsigned)f2bf(f.x) | ((unsigned)f2bf(f.y) << 16);
        p.y = (unsigned)f2bf(f.z) | ((unsigned)f2bf(f.w) << 16);
        ((uint2*)dst)[i] = p;
    }
}

// One phase of the 8-phase schedule: {ds-read frags | stage 1 half-tile |
// barrier | lgkmcnt(0) | setprio(1) 16 MFMA setprio(0) | [vmcnt(N)] | barrier}
template<bool LOADA, int NB0>
__device__ __forceinline__ void phase(const char* regA, const char* regB,
    int offA, int offB, bf16x8 (&a)[8], f32x4 (&acc)[8][4],
    const char* gsrc, char* ldst, bool do_stage, int vmN)
{
    if (LOADA) {
#pragma unroll
        for (int m = 0; m < 8; ++m) a[m] = *(const bf16x8*)(regA + offA + m * 1024);
    }
    bf16x8 b0 = *(const bf16x8*)(regB + offB + (NB0)     * 1024);
    bf16x8 b1 = *(const bf16x8*)(regB + offB + (NB0 + 1) * 1024);
    if (do_stage) { GLOAD16(gsrc, ldst); GLOAD16(gsrc + 131072, ldst + 8192); }
    __builtin_amdgcn_s_barrier();
    asm volatile("s_waitcnt lgkmcnt(0)" ::: "memory");
    __builtin_amdgcn_sched_barrier(0);
    __builtin_amdgcn_s_setprio(1);
#pragma unroll
    for (int m = 0; m < 8; ++m) {
        acc[m][NB0]     = __builtin_amdgcn_mfma_f32_16x16x32_bf16(a[m], b0, acc[m][NB0],     0, 0, 0);
        acc[m][NB0 + 1] = __builtin_amdgcn_mfma_f32_16x16x32_bf16(a[m], b1, acc[m][NB0 + 1], 0, 0, 0);
    }
    __builtin_amdgcn_s_setprio(0);
    if (vmN == 8)      asm volatile("s_waitcnt vmcnt(8)" ::: "memory");
    else if (vmN == 4) asm volatile("s_waitcnt vmcnt(4)" ::: "memory");
    else if (vmN == 0) asm volatile("s_waitcnt vmcnt(0)" ::: "memory");
    __builtin_amdgcn_s_barrier();
}

// bf16 MFMA GEMM sim = Rb [NB x DD] @ Cb^T [KC x DD], 256x256 tile, BK=64,
// 8 waves (2x4), m201-style 8-phase schedule with counted vmcnt(8), LDS as
// 8 half-tile regions [256 rows][32 k] (A/B x khalf x dbuf), XOR-swizzled
// source staging. Fused per-row top-2 per 128-code half -> part[NB][32].
__global__ __launch_bounds__(512, 2)
void k_simtop2(const u16* __restrict__ Rb, const u16* __restrict__ Cb,
               Top2* __restrict__ part /* [NB][NTB] */)
{
    extern __shared__ char lds[];   // 8 regions x 16 KB = 128 KB
    const int tid  = threadIdx.x;
    const int lane = tid & 63;
    const int w    = tid >> 6;        // 0..7
    const int wm   = w >> 2;          // 0..1  (row half)
    const int wn   = w & 3;           // 0..3  (col quarter)

    // XCD chunking: 512 blocks -> 8 chunks of 8x8 tiles (A 2MB + B 2MB ~ L2)
    const int bid = blockIdx.x;
    const int xcd = bid & 7;
    const int idx = bid >> 3;                       // 0..63
    const int row_pan  = (xcd >> 1) * 8 + (idx >> 3);   // 0..31
    const int col_tile = (xcd & 1) * 8 + (idx & 7);     // 0..15
    const int rb0 = row_pan * GBM;
    const int cb0 = col_tile * GBN;

    // staging addressing: region = [256 rows][4 x 16B k-chunks]; thread covers
    // rows rr0=tid>>2 and rr0+128; LDS dest linear (tid*16, +8192); global
    // source chunk = s ^ ((row>>1)&3)  (same for both rows; reader inverts)
    const int rr0 = tid >> 2;
    const int sg  = (tid & 3) ^ ((rr0 >> 1) & 3);
    const char* gA0 = (const char*)Rb + (size_t)(rb0 + rr0) * 1024 + sg * 16;
    const char* gB0 = (const char*)Cb + (size_t)(cb0 + rr0) * 1024 + sg * 16;
#define REGN(r) (lds + (r) * 16384)
#define LDST(r) (lds + (r) * 16384 + (tid << 4))

    // fragment read offsets: row_local*64 + ((ks ^ ((row>>1)&3))<<4)
    const int la = lane & 15, ks = lane >> 4;
    const int swz = (la >> 1) & 3;
    const int offA = (wm * 128 + la) * 64 + ((ks ^ swz) << 4);
    const int offB = (wn * 64  + la) * 64 + ((ks ^ swz) << 4);

    f32x4 acc[8][4];
    const f32x4 zero = {0.f, 0.f, 0.f, 0.f};
#pragma unroll
    for (int m = 0; m < 8; ++m)
#pragma unroll
        for (int n = 0; n < 4; ++n) acc[m][n] = zero;
    bf16x8 a[8];

#define STAGE2(R, SRC) do { GLOAD16((SRC), LDST(R)); GLOAD16((SRC) + 131072, LDST(R) + 8192); } while (0)
    // prologue: tile0 {A,B}x{k0,k1} -> r0..r3; tile1 {A,B}k0 -> r4,r5
    STAGE2(0, gA0);
    STAGE2(1, gB0);
    STAGE2(2, gA0 + 64);
    STAGE2(3, gB0 + 64);
    STAGE2(4, gA0 + 128);
    STAGE2(5, gB0 + 128);
    asm volatile("s_waitcnt vmcnt(8)" ::: "memory");   // r0,r1 landed
    __builtin_amdgcn_s_barrier();

#pragma unroll 1
    for (int t = 0; t < 4; ++t) {           // 2 K-tiles (BK=64) per iteration
        const int o1 = 2 * t + 1, e2 = 2 * t + 2, o3 = 2 * t + 3;
        const bool s2 = (t < 3);
        // ledger: reads p1/p2:r0,r1  p3/p4:r2,r3  p5/p6:r4,r5  p7/p8:r6,r7
        // stages: p1->r6(A o1 k1) p2->r7(B o1 k1) p3->r0(A e2 k0) p4->r1(B e2 k0)
        //         p5->r2(A e2 k1) p6->r3(B e2 k1) p7->r4(A o3 k0) p8->r5(B o3 k0)
        // vmcnt(8) at every even phase guards the half-tiles staged 4 phases ago.
        phase<true , 0>(REGN(0), REGN(1), offA, offB, a, acc, gA0 + o1 * 128 + 64, LDST(6), true, -1);
        phase<false, 2>(REGN(0), REGN(1), offA, offB, a, acc, gB0 + o1 * 128 + 64, LDST(7), true, 8);
        phase<true , 0>(REGN(2), REGN(3), offA, offB, a, acc, gA0 + e2 * 128,      LDST(0), s2, -1);
        phase<false, 2>(REGN(2), REGN(3), offA, offB, a, acc, gB0 + e2 * 128,      LDST(1), s2, s2 ? 8 : 4);
        phase<true , 0>(REGN(4), REGN(5), offA, offB, a, acc, gA0 + e2 * 128 + 64, LDST(2), s2, -1);
        phase<false, 2>(REGN(4), REGN(5), offA, offB, a, acc, gB0 + e2 * 128 + 64, LDST(3), s2, s2 ? 8 : 0);
        phase<true , 0>(REGN(6), REGN(7), offA, offB, a, acc, gA0 + o3 * 128,      LDST(4), s2, -1);
        phase<false, 2>(REGN(6), REGN(7), offA, offB, a, acc, gB0 + o3 * 128,      LDST(5), s2, s2 ? 8 : -1);
    }
#undef STAGE2

    __syncthreads();                        // LDS now free; reuse for merge
    Top2 (*mrg)[4] = (Top2 (*)[4])lds;      // [256 rows][4 wave-cols] = 16 KB

    // epilogue: C row = (lane>>4)*4 + j (batch), col = lane&15 (code)
    const int rgrp = lane >> 4;
    const int cidx = lane & 15;
#pragma unroll
    for (int m = 0; m < 8; ++m) {
#pragma unroll
        for (int j = 0; j < 4; ++j) {
            float v1 = -INFINITY, v2 = -INFINITY;
            int   i1 = 0x7fffffff, i2 = 0x7fffffff;
#pragma unroll
            for (int n = 0; n < 4; ++n)
                top2_insert(acc[m][n][j], cb0 + wn * 64 + n * 16 + cidx, v1, i1, v2, i2);
            for (int off = 1; off < 16; off <<= 1) {
                float ov1 = __shfl_xor(v1, off); int oi1 = __shfl_xor(i1, off);
                float ov2 = __shfl_xor(v2, off); int oi2 = __shfl_xor(i2, off);
                if (ov1 > v1 || (ov1 == v1 && oi1 < i1)) {
                    float nv2; int ni2; pick_better(v1, i1, ov2, oi2, nv2, ni2);
                    v1 = ov1; i1 = oi1; v2 = nv2; i2 = ni2;
                } else {
                    float nv2; int ni2; pick_better(v2, i2, ov1, oi1, nv2, ni2);
                    v2 = nv2; i2 = ni2;
                }
            }
            if (cidx == 0) {
                Top2 p; p.v1 = v1; p.i1 = i1; p.v2 = v2; p.i2 = i2;
                mrg[wm * 128 + m * 16 + rgrp * 4 + j][wn] = p;
            }
        }
    }
    __syncthreads();
    if (tid < 256) {   // per 128-code half: identical candidate structure to R2/R3
        Top2 x0 = mrg[tid][0], x1 = mrg[tid][1];
        float v1 = x0.v1, v2 = x0.v2; int i1 = x0.i1, i2 = x0.i2;
        top2_insert(x1.v1, x1.i1, v1, i1, v2, i2);
        top2_insert(x1.v2, x1.i2, v1, i1, v2, i2);
        Top2 p; p.v1 = v1; p.i1 = i1; p.v2 = v2; p.i2 = i2;
        part[(size_t)(rb0 + tid) * NTB + col_tile * 2] = p;
        Top2 y0 = mrg[tid][2], y1 = mrg[tid][3];
        v1 = y0.v1; v2 = y0.v2; i1 = y0.i1; i2 = y0.i2;
        top2_insert(y1.v1, y1.i1, v1, i1, v2, i2);
        top2_insert(y1.v2, y1.i2, v1, i1, v2, i2);
        p.v1 = v1; p.i1 = i1; p.v2 = v2; p.i2 = i2;
        part[(size_t)(rb0 + tid) * NTB + col_tile * 2 + 1] = p;
    }
#undef REGN
#undef LDST
}

// Per row: exact fp32 re-dot of candidates within MARGIN of the bf16 max, argmax,
// residual update (fp32 chain via out_stack + bf16 mirror), per-block loss partial
// (no atomics), usage; layer NL-1 also writes quantized = x - r.
__global__ __launch_bounds__(256)
void k_refine(const Top2* __restrict__ part, const float* __restrict__ CB,
              const float* __restrict__ prevBase, size_t prevStride,
              const float* __restrict__ X, float* __restrict__ out_q,
              float* __restrict__ stack, u16* __restrict__ residb,
              float* __restrict__ out_usage, float* __restrict__ pl,
              int layer)
{
    __shared__ float row[DD];
    __shared__ float candV[64];
    __shared__ int   candI[64];
    __shared__ float s_thr;
    __shared__ float wbv[4];
    __shared__ int   wbi[4];
    __shared__ int   s_best;
    __shared__ float red[256];

    const int b = blockIdx.x;
    const int tid = threadIdx.x;
    const float* pr = prevBase + (size_t)b * prevStride;
    row[tid]       = pr[tid];
    row[tid + 256] = pr[tid + 256];
    if (tid < 64) {
        Top2 p = part[(size_t)b * NTB + (tid >> 1)];
        candV[tid] = (tid & 1) ? p.v2 : p.v1;
        candI[tid] = (tid & 1) ? p.i2 : p.i1;
    }
    __syncthreads();
    if (tid < 64) {
        float v = candV[tid];
        for (int off = 1; off < 64; off <<= 1) v = fmaxf(v, __shfl_xor(v, off));
        if (tid == 0) s_thr = v - MARGIN;
    }
    __syncthreads();
    const float thr = s_thr;

    const int wave = tid >> 6;
    const int lane = tid & 63;
    float bestV = -INFINITY;
    int   bestI = 0x7fffffff;
    for (int s = 0; s < 16; ++s) {
        const int c = wave * 16 + s;
        if (candV[c] < thr) continue;          // wave-uniform skip
        const int ci = candI[c];
        const float* cr = CB + (size_t)ci * DD;
        float p = 0.f;
#pragma unroll
        for (int q = 0; q < 8; ++q)
            p = fmaf(row[lane * 8 + q], cr[lane * 8 + q], p);
        for (int off = 32; off >= 1; off >>= 1) p += __shfl_xor(p, off);
        if (p > bestV || (p == bestV && ci < bestI)) { bestV = p; bestI = ci; }
    }
    if (lane == 0) { wbv[wave] = bestV; wbi[wave] = bestI; }
    __syncthreads();
    if (tid == 0) {
        float bv = wbv[0]; int bi = wbi[0];
        for (int k = 1; k < 4; ++k)
            if (wbv[k] > bv || (wbv[k] == bv && wbi[k] < bi)) { bv = wbv[k]; bi = wbi[k]; }
        s_best = bi;
        out_usage[layer * KC + bi] = 1.0f;
    }
    __syncthreads();
    const int bi = s_best;

    const float* cr = CB + (size_t)bi * DD;
    const float rn0 = row[tid]       - cr[tid];
    const float rn1 = row[tid + 256] - cr[tid + 256];
    float* sp = stack + ((size_t)b * NL + layer) * DD;   // base odd-aligned -> scalar
    sp[tid]       = rn0;
    sp[tid + 256] = rn1;
    residb[(size_t)b * DD + tid]       = f2bf(rn0);
    residb[(size_t)b * DD + tid + 256] = f2bf(rn1);
    if (layer == NL - 1) {
        out_q[(size_t)b * DD + tid]       = X[(size_t)b * DD + tid]       - rn0;
        out_q[(size_t)b * DD + tid + 256] = X[(size_t)b * DD + tid + 256] - rn1;
    }
    red[tid] = rn0 * rn0 + rn1 * rn1;
    __syncthreads();
    for (int st = 128; st > 0; st >>= 1) {
        if (tid < st) red[tid] += red[tid + st];
        __syncthreads();
    }
    if (tid == 0) pl[(size_t)layer * NB + b] = red[0];
}

__global__ __launch_bounds__(256)
void k_cbsq(const float* __restrict__ cb, double* __restrict__ cq)
{
    __shared__ double red[256];
    const size_t n = (size_t)NL * KC * DD;
    double s = 0.0;
    for (size_t i = (size_t)blockIdx.x * blockDim.x + threadIdx.x; i < n;
         i += (size_t)gridDim.x * blockDim.x) {
        const float v = cb[i];
        s += (double)v * (double)v;
    }
    red[threadIdx.x] = s;
    __syncthreads();
    for (int st = 128; st > 0; st >>= 1) {
        if (threadIdx.x < st) red[threadIdx.x] += red[threadIdx.x + st];
        __syncthreads();
    }
    if (threadIdx.x == 0) cq[blockIdx.x] = red[0];
}

__global__ __launch_bounds__(256)
void k_finalize(const float* __restrict__ pl, const double* __restrict__ cq,
                float* __restrict__ out_loss)
{
    __shared__ double red[256];
    const int tid = threadIdx.x;
    double s = 0.0;
    for (int i = tid; i < NL * NB; i += 256) s += (double)pl[i];
    double s2 = 0.0;
    for (int i = tid; i < 1024; i += 256) s2 += cq[i];
    red[tid] = s / ((double)NB * DD) + 0.01 * (s2 / ((double)NL * KC));
    __syncthreads();
    for (int st = 128; st > 0; st >>= 1) {
        if (tid < st) red[tid] += red[tid + st];
        __syncthreads();
    }
    if (tid == 0) out_loss[0] = (float)(red[0] / (double)DD);
}

extern "C" void kernel_launch(void* const* d_in, const int* in_sizes, int n_in,
                              void* d_out, int out_size, void* d_ws, size_t ws_size,
                              hipStream_t stream)
{
    (void)in_sizes; (void)n_in; (void)out_size; (void)ws_size;
    const float* x  = (const float*)d_in[0];
    // d_in[1] = temperature: positive scale, argmax-invariant, soft path cancels -> unused
    const float* cb = (const float*)d_in[2];

    float* out       = (float*)d_out;
    float* out_q     = out;                                   // [NB, DD]
    float* out_loss  = out + (size_t)NB * DD;                 // [1]
    float* out_stack = out_loss + 1;                          // [NB, NL, DD] (fp32 residual chain)
    float* out_usage = out_stack + (size_t)NB * NL * DD;      // [NL, KC]

    char* ws = (char*)d_ws;
    Top2*  part   = (Top2*)ws;                                // 4 MB
    u16*   residb = (u16*)(ws + ((size_t)4 << 20));           // 8 MB bf16 residual mirror
    u16*   cbb    = (u16*)(ws + ((size_t)12 << 20));          // 4 MB bf16 codebook (per layer)
    float* pl     = (float*)(ws + ((size_t)16 << 20));        // NL*NB loss partials (128 KB)
    double* cq    = (double*)(ws + ((size_t)16 << 20) + 131072 + 256); // 1024 cbsq partials

    hipFuncSetAttribute((const void*)k_simtop2,
                        hipFuncAttributeMaxDynamicSharedMemorySize, 131072);

    hipMemsetAsync(out_usage, 0, (size_t)NL * KC * sizeof(float), stream);

    k_cvt_bf16<<<(NB * DD / 4 + 255) / 256, 256, 0, stream>>>(x, residb, NB * DD / 4);
    k_cbsq<<<1024, 256, 0, stream>>>(cb, cq);

    for (int l = 0; l < NL; ++l) {
        const float* cbl = cb + (size_t)l * KC * DD;
        k_cvt_bf16<<<(KC * DD / 4 + 255) / 256, 256, 0, stream>>>(cbl, cbb, KC * DD / 4);
        k_simtop2<<<512, 512, 131072, stream>>>(residb, cbb, part);
        const float* prevBase = (l == 0) ? x : (out_stack + (size_t)(l - 1) * DD);
        const size_t prevStride = (l == 0) ? (size_t)DD : (size_t)NL * DD;
        k_refine<<<NB, 256, 0, stream>>>(part, cbl, prevBase, prevStride, x, out_q,
                                         out_stack, residb, out_usage, pl, l);
    }
    k_finalize<<<1, 256, 0, stream>>>(pl, cq, out_loss);
}